// Round 17
// baseline (127.810 us; speedup 1.0000x reference)
//
#include <hip/hip_runtime.h>
#include <hip/hip_bf16.h>
#include <hip/hip_fp16.h>
#include <cstddef>
#include <cstdint>

// Hyena1D: y = irfft(rfft(x, axis=1) * H) * amp_gain, H real per (bin, channel).
//
// Channel-pair packing: z_g(t) = x[t][2g] + i*x[t][2g+1];
//   Y[k] = hp*Z[k] + hm*conj(Z[4096-k]), hp=(HA+HB)/2, hm=(HA-HB)/2.
// Pipeline: T1 transpose -> F fused radix-16^3 FFT/filter/iFFT -> T2 transpose.
//
// r17 = r16 champion + PARTNER-FROM-V2: the conjugate partner X[4096-k] is
// computed directly from the stage-2 LDS image (one extra column read + one
// extra dft16 per thread) instead of writing X to LDS and reading it back.
// Digit algebra: k = rr+16ii+256s2 -> kp=4096-k has per-thread-FIXED column
// (r',i') = rr>0 ? (16-rr,15-ii) : ii>0 ? (0,16-ii) : (0,0)[tid0=own col],
// with s2' = 15-s2 (tid0: (16-s2)&15). Removes the filter write+barrier+read:
// 9 barriers -> 7, 5 LDS round-trips -> 4, -16 LDS writes, +1 dft16 (+12%
// VALU). Kernel is ~45% barrier-stall -> net win expected.
// Session lessons: no VGPR squeeze, no fp16 LDS, no twiddle tables, grid
// (D2_,B_) for same-XCD HT reuse, 1/4096 folded into HT.

#define B_ 4
#define T_ 4096
#define D_ 1024
#define D2_ 512
#define NBINS 2049

constexpr float WC16[8] = {1.f, 0.9238795325112867f, 0.7071067811865476f,
                           0.3826834323650898f, 0.f, -0.3826834323650898f,
                           -0.7071067811865476f, -0.9238795325112867f};
constexpr float WS16[8] = {0.f, 0.3826834323650898f, 0.7071067811865476f,
                           0.9238795325112867f, 1.f, 0.9238795325112867f,
                           0.7071067811865476f, 0.3826834323650898f};

template <int SGN>
__device__ __forceinline__ void dft16(float (&vr)[16], float (&vi)[16]) {
#pragma unroll
  for (int i = 0; i < 16; ++i) {
    const int j = ((i & 1) << 3) | ((i & 2) << 1) | ((i & 4) >> 1) | ((i & 8) >> 3);
    if (j > i) {
      float t = vr[i]; vr[i] = vr[j]; vr[j] = t;
      t = vi[i]; vi[i] = vi[j]; vi[j] = t;
    }
  }
#pragma unroll
  for (int s = 1; s <= 4; ++s) {
    const int L = 1 << s, hh = L >> 1, step = 16 >> s;
#pragma unroll
    for (int k0 = 0; k0 < 16; k0 += L)
#pragma unroll
      for (int j = 0; j < hh; ++j) {
        const float wr = WC16[j * step];
        const float wi = (float)SGN * WS16[j * step];
        const int ia = k0 + j, ib = ia + hh;
        const float tr = wr * vr[ib] - wi * vi[ib];
        const float ti = wr * vi[ib] + wi * vr[ib];
        vr[ib] = vr[ia] - tr; vi[ib] = vi[ia] - ti;
        vr[ia] += tr; vi[ia] += ti;
      }
  }
}

__device__ __forceinline__ void twiddle(float& xr, float& xi, float ang) {
  float sn, cs;
  __sincosf(ang, &sn, &cs);
  const float r = xr * cs - xi * sn;
  xi = xr * sn + xi * cs;
  xr = r;
}

__device__ __forceinline__ uint32_t pk(float r, float i) {
  const __half2 h = __floats2half2_rn(r, i);
  return *(const uint32_t*)&h;
}
__device__ __forceinline__ float2 upk(uint32_t u) {
  const __half2 h = *(const __half2*)&u;
  return __half22float2(h);
}

// ---- filter MLP ----
__global__ void k_filter_h(const float* __restrict__ W1, const float* __restrict__ b1,
                           float* __restrict__ h) {
  const int bin = blockIdx.x * 256 + threadIdx.x;
  if (bin >= NBINS) return;
  constexpr float invf[8] = {1.0f, 0.31622776601683794f, 0.1f, 0.031622776601683794f,
                             0.01f, 3.1622776601683794e-3f, 1.0e-3f, 3.1622776601683794e-4f};
  float pe[16];
#pragma unroll
  for (int i = 0; i < 8; ++i) {
    const float a = (float)bin * invf[i];
    pe[2 * i] = sinf(a);
    pe[2 * i + 1] = cosf(a);
  }
#pragma unroll
  for (int m = 0; m < 32; ++m) {
    float s = b1[m];
#pragma unroll
    for (int i = 0; i < 16; ++i) s += pe[i] * W1[i * 32 + m];
    h[bin * 32 + m] = s / (1.0f + expf(-s));  // silu
  }
}

// HT[g][bin] = (hp, hm) pre-scaled by 1/4096
__global__ void k_filter_HT(const float* __restrict__ h, const float* __restrict__ W2,
                            const float* __restrict__ b2, float2* __restrict__ HT) {
  const int bin = blockIdx.x * 256 + threadIdx.x;
  const int g = blockIdx.y;
  if (bin >= NBINS) return;
  float sA = b2[2 * g], sB = b2[2 * g + 1];
#pragma unroll
  for (int m = 0; m < 32; ++m) {
    const float hv = h[bin * 32 + m];
    sA += hv * W2[m * D_ + 2 * g];
    sB += hv * W2[m * D_ + 2 * g + 1];
  }
  constexpr float sc = 0.5f / 4096.0f;
  HT[(size_t)g * NBINS + bin] = make_float2((sA + sB) * sc, (sA - sB) * sc);
}

// ---- T1: x[b,t,d] -> Z[b,g,t] (packed pairs, fp16 half2) ----
__global__ __launch_bounds__(256, 8) void k_pack_t(const float2* __restrict__ x2,
                                                   uint32_t* __restrict__ Z) {
  __shared__ float2 tile[64][33];
  const int tid = threadIdx.x;
  const int g0 = blockIdx.x * 32;
  const int t0 = blockIdx.y * 64;
  const int b = blockIdx.z;
#pragma unroll
  for (int it = 0; it < 8; ++it) {
    const int l = tid + 256 * it;
    const int r = l >> 5, c = l & 31;
    tile[r][c] = x2[((size_t)b * T_ + t0 + r) * D2_ + g0 + c];
  }
  __syncthreads();
#pragma unroll
  for (int it = 0; it < 8; ++it) {
    const int l = tid + 256 * it;
    const int gg = l >> 6, tt = l & 63;
    const float2 t = tile[tt][gg];
    Z[((size_t)b * D2_ + g0 + gg) * T_ + t0 + tt] = pk(t.x, t.y);
  }
}

// ---- F: full FFT/filter/iFFT per (g,b), in-place on fp16 Z row ----
__global__ __launch_bounds__(256, 4) void k_fft_fused(uint32_t* __restrict__ Z,
                                                      const float2* __restrict__ HT) {
  __shared__ float2 S[4096];  // 32 KB fp32
  const int tid = threadIdx.x;
  const int g = blockIdx.x;
  const int b = blockIdx.y;
  uint32_t* __restrict__ Zrow = Z + ((size_t)b * D2_ + g) * T_;
  const float2* __restrict__ HTg = HT + (size_t)g * NBINS;
  constexpr float C1f = -6.28318530717958647692f / 4096.0f;
  constexpr float C2f = -6.28318530717958647692f / 256.0f;
  constexpr float C1i = 6.28318530717958647692f / 4096.0f;
  constexpr float C2i = 6.28318530717958647692f / 256.0f;

  float vr[16], vi[16];
  // fwd stage 1: thread j: u[a]=z[j+256a]; DFT16 a->r; *W4096^{-rj}; S[256r+j]
  {
    const int j = tid;
#pragma unroll
    for (int a = 0; a < 16; ++a) {
      const float2 t = upk(Zrow[j + 256 * a]);
      vr[a] = t.x; vi[a] = t.y;
    }
    dft16<-1>(vr, vi);
#pragma unroll
    for (int r = 1; r < 16; ++r) twiddle(vr[r], vi[r], C1f * (float)(r * j));
#pragma unroll
    for (int r = 0; r < 16; ++r) S[256 * r + j] = make_float2(vr[r], vi[r]);
  }
  __syncthreads();  // [B1]
  const int rr = tid >> 4, ii = tid & 15;
  // fwd stage 2
  {
#pragma unroll
    for (int a = 0; a < 16; ++a) {
      const float2 t = S[256 * rr + ii + 16 * a];
      vr[a] = t.x; vi[a] = t.y;
    }
    __syncthreads();  // [B2] WAR
    dft16<-1>(vr, vi);
#pragma unroll
    for (int r2 = 1; r2 < 16; ++r2) twiddle(vr[r2], vi[r2], C2f * (float)(r2 * ii));
#pragma unroll
    for (int r2 = 0; r2 < 16; ++r2)
      S[256 * ii + 16 * rr + (r2 ^ ii)] = make_float2(vr[r2], vi[r2]);
  }
  __syncthreads();  // [B3]
  // fwd stage 3 + partner + filter: both columns read from the stage-2 image.
  // Partner column (rp, ip): fixed per thread (see header); tid0 = own column.
  {
    const int rp = (rr > 0) ? (16 - rr) : 0;
    const int ip = (rr > 0) ? (15 - ii) : ((ii > 0) ? (16 - ii) : 0);
    float pr[16], pi[16];
#pragma unroll
    for (int i2 = 0; i2 < 16; ++i2) {
      const float2 t = S[256 * i2 + 16 * rr + (ii ^ i2)];
      vr[i2] = t.x; vi[i2] = t.y;
    }
#pragma unroll
    for (int i2 = 0; i2 < 16; ++i2) {
      const float2 t = S[256 * i2 + 16 * rp + (ip ^ i2)];
      pr[i2] = t.x; pi[i2] = t.y;
    }
    dft16<-1>(vr, vi);  // vr[s2] = X[k], k = rr + 16*ii + 256*s2
    dft16<-1>(pr, pi);  // pr[s2'] = X[rp + 16*ip + 256*s2']
#pragma unroll
    for (int s2 = 0; s2 < 16; ++s2) {
      const int k = rr + 16 * ii + 256 * s2;
      const int km = (k <= 2048) ? k : 4096 - k;
      const float2 hv = HTg[km];
      const float xpr = (tid == 0) ? pr[(16 - s2) & 15] : pr[15 - s2];
      const float xpi = (tid == 0) ? pi[(16 - s2) & 15] : pi[15 - s2];
      const float yr = hv.x * vr[s2] + hv.y * xpr;
      const float yi = hv.x * vi[s2] - hv.y * xpi;
      vr[s2] = yr; vi[s2] = yi;
    }
  }
  // inv stage A (compute before the WAR barrier; writes after)
  {
    dft16<1>(vr, vi);
#pragma unroll
    for (int j0 = 1; j0 < 16; ++j0) twiddle(vr[j0], vi[j0], C2i * (float)(ii * j0));
  }
  __syncthreads();  // [B4] WAR: all stage-3 reads done before invA writes
  {
#pragma unroll
    for (int j0 = 0; j0 < 16; ++j0)
      S[256 * j0 + 16 * rr + (ii ^ j0)] = make_float2(vr[j0], vi[j0]);
  }
  __syncthreads();  // [B5]
  // inv stage B
  {
#pragma unroll
    for (int r2 = 0; r2 < 16; ++r2) {
      const float2 t = S[256 * ii + 16 * rr + (r2 ^ ii)];
      vr[r2] = t.x; vi[r2] = t.y;
    }
    __syncthreads();  // [B6] WAR
    dft16<1>(vr, vi);
#pragma unroll
    for (int j1 = 0; j1 < 16; ++j1)
      twiddle(vr[j1], vi[j1], C1i * (float)(rr * (ii + 16 * j1)));
#pragma unroll
    for (int j1 = 0; j1 < 16; ++j1)
      S[256 * rr + ii + 16 * j1] = make_float2(vr[j1], vi[j1]);
  }
  __syncthreads();  // [B7]
  // inv stage C: thread j: u[r]=S[256r+j]; DFT16; z[j+256a] (1/N in HT)
  {
    const int j = tid;
#pragma unroll
    for (int r = 0; r < 16; ++r) {
      const float2 t = S[256 * r + j];
      vr[r] = t.x; vi[r] = t.y;
    }
    dft16<1>(vr, vi);
#pragma unroll
    for (int a = 0; a < 16; ++a)
      Zrow[j + 256 * a] = pk(vr[a], vi[a]);
  }
}

// ---- T2: Z[b,g,t] (fp16) -> y[b,t,d], * amp ----
__global__ __launch_bounds__(256, 8) void k_unpack_t(const uint32_t* __restrict__ Z,
                                                     const float2* __restrict__ amp2,
                                                     float2* __restrict__ y2) {
  __shared__ float2 tile[64][33];
  const int tid = threadIdx.x;
  const int g0 = blockIdx.x * 32;
  const int t0 = blockIdx.y * 64;
  const int b = blockIdx.z;
#pragma unroll
  for (int it = 0; it < 8; ++it) {
    const int l = tid + 256 * it;
    const int gg = l >> 6, tt = l & 63;
    tile[tt][gg] = upk(Z[((size_t)b * D2_ + g0 + gg) * T_ + t0 + tt]);
  }
  __syncthreads();
#pragma unroll
  for (int it = 0; it < 8; ++it) {
    const int l = tid + 256 * it;
    const int r = l >> 5, c = l & 31;
    const float2 t = tile[r][c];
    const float2 av = amp2[g0 + c];
    y2[((size_t)b * T_ + t0 + r) * D2_ + g0 + c] = make_float2(t.x * av.x, t.y * av.y);
  }
}

extern "C" void kernel_launch(void* const* d_in, const int* in_sizes, int n_in,
                              void* d_out, int out_size, void* d_ws, size_t ws_size,
                              hipStream_t stream) {
  const float* x = (const float*)d_in[0];
  const float* W1 = (const float*)d_in[1];
  const float* b1 = (const float*)d_in[2];
  const float* W2 = (const float*)d_in[3];
  const float* b2 = (const float*)d_in[4];
  const float* amp = (const float*)d_in[5];
  float* out = (float*)d_out;

  uint32_t* Z = (uint32_t*)d_ws;  // 32 MB (fp16 half2)
  float2* HT = (float2*)((char*)d_ws + (size_t)B_ * D2_ * T_ * sizeof(uint32_t));  // 8.4 MB
  float* h = (float*)((char*)HT + (size_t)D2_ * NBINS * sizeof(float2));  // 262 KB

  k_filter_h<<<dim3((NBINS + 255) / 256), 256, 0, stream>>>(W1, b1, h);
  k_filter_HT<<<dim3((NBINS + 255) / 256, D2_), 256, 0, stream>>>(h, W2, b2, HT);
  k_pack_t<<<dim3(D2_ / 32, T_ / 64, B_), 256, 0, stream>>>((const float2*)x, Z);
  k_fft_fused<<<dim3(D2_, B_), 256, 0, stream>>>(Z, HT);
  k_unpack_t<<<dim3(D2_ / 32, T_ / 64, B_), 256, 0, stream>>>(Z, (const float2*)amp,
                                                              (float2*)out);
}

// Round 18
// 101.517 us; speedup vs baseline: 1.2590x; 1.2590x over previous
//
#include <hip/hip_runtime.h>
#include <hip/hip_bf16.h>
#include <hip/hip_fp16.h>
#include <cstddef>
#include <cstdint>

// Hyena1D: y = irfft(rfft(x, axis=1) * H) * amp_gain, H real per (bin, channel).
//
// Channel-pair packing: z_g(t) = x[t][2g] + i*x[t][2g+1];
//   Y[k] = hp*Z[k] + hm*conj(Z[4096-k]), hp=(HA+HB)/2, hm=(HA-HB)/2.
// Pipeline: T1 transpose -> F fused radix-16^3 FFT/filter/iFFT -> T2 transpose.
//
// CHAMPION (r16, 101.6us): fp32 LDS, fp16 Z, on-the-fly sincos, 9 barriers,
// grid (D2_,B_), launch_bounds(256,4), 1/4096 folded into HT.
// r17 post-mortem: partner-from-V2 (+32 live floats) -> spill (FETCH 86MB,
// WRITE 153MB), 6th spill trap. Reverted. Structural floor arithmetic:
// satellites 34us = pure BW; fused 67us = 10 traffic + 27 VALU + 30 barrier
// latency; all levers on the 30us (occupancy r10/13/14, ILP r8/11, op-count
// r9/15, barriers r17) measured as losses on this toolchain.

#define B_ 4
#define T_ 4096
#define D_ 1024
#define D2_ 512
#define NBINS 2049

constexpr float WC16[8] = {1.f, 0.9238795325112867f, 0.7071067811865476f,
                           0.3826834323650898f, 0.f, -0.3826834323650898f,
                           -0.7071067811865476f, -0.9238795325112867f};
constexpr float WS16[8] = {0.f, 0.3826834323650898f, 0.7071067811865476f,
                           0.9238795325112867f, 1.f, 0.9238795325112867f,
                           0.7071067811865476f, 0.3826834323650898f};

template <int SGN>
__device__ __forceinline__ void dft16(float (&vr)[16], float (&vi)[16]) {
#pragma unroll
  for (int i = 0; i < 16; ++i) {
    const int j = ((i & 1) << 3) | ((i & 2) << 1) | ((i & 4) >> 1) | ((i & 8) >> 3);
    if (j > i) {
      float t = vr[i]; vr[i] = vr[j]; vr[j] = t;
      t = vi[i]; vi[i] = vi[j]; vi[j] = t;
    }
  }
#pragma unroll
  for (int s = 1; s <= 4; ++s) {
    const int L = 1 << s, hh = L >> 1, step = 16 >> s;
#pragma unroll
    for (int k0 = 0; k0 < 16; k0 += L)
#pragma unroll
      for (int j = 0; j < hh; ++j) {
        const float wr = WC16[j * step];
        const float wi = (float)SGN * WS16[j * step];
        const int ia = k0 + j, ib = ia + hh;
        const float tr = wr * vr[ib] - wi * vi[ib];
        const float ti = wr * vi[ib] + wi * vr[ib];
        vr[ib] = vr[ia] - tr; vi[ib] = vi[ia] - ti;
        vr[ia] += tr; vi[ia] += ti;
      }
  }
}

__device__ __forceinline__ void twiddle(float& xr, float& xi, float ang) {
  float sn, cs;
  __sincosf(ang, &sn, &cs);
  const float r = xr * cs - xi * sn;
  xi = xr * sn + xi * cs;
  xr = r;
}

__device__ __forceinline__ uint32_t pk(float r, float i) {
  const __half2 h = __floats2half2_rn(r, i);
  return *(const uint32_t*)&h;
}
__device__ __forceinline__ float2 upk(uint32_t u) {
  const __half2 h = *(const __half2*)&u;
  return __half22float2(h);
}

// ---- filter MLP ----
__global__ void k_filter_h(const float* __restrict__ W1, const float* __restrict__ b1,
                           float* __restrict__ h) {
  const int bin = blockIdx.x * 256 + threadIdx.x;
  if (bin >= NBINS) return;
  constexpr float invf[8] = {1.0f, 0.31622776601683794f, 0.1f, 0.031622776601683794f,
                             0.01f, 3.1622776601683794e-3f, 1.0e-3f, 3.1622776601683794e-4f};
  float pe[16];
#pragma unroll
  for (int i = 0; i < 8; ++i) {
    const float a = (float)bin * invf[i];
    pe[2 * i] = sinf(a);
    pe[2 * i + 1] = cosf(a);
  }
#pragma unroll
  for (int m = 0; m < 32; ++m) {
    float s = b1[m];
#pragma unroll
    for (int i = 0; i < 16; ++i) s += pe[i] * W1[i * 32 + m];
    h[bin * 32 + m] = s / (1.0f + expf(-s));  // silu
  }
}

// HT[g][bin] = (hp, hm) pre-scaled by 1/4096 (fp32 table: no range concern)
__global__ void k_filter_HT(const float* __restrict__ h, const float* __restrict__ W2,
                            const float* __restrict__ b2, float2* __restrict__ HT) {
  const int bin = blockIdx.x * 256 + threadIdx.x;
  const int g = blockIdx.y;
  if (bin >= NBINS) return;
  float sA = b2[2 * g], sB = b2[2 * g + 1];
#pragma unroll
  for (int m = 0; m < 32; ++m) {
    const float hv = h[bin * 32 + m];
    sA += hv * W2[m * D_ + 2 * g];
    sB += hv * W2[m * D_ + 2 * g + 1];
  }
  constexpr float sc = 0.5f / 4096.0f;
  HT[(size_t)g * NBINS + bin] = make_float2((sA + sB) * sc, (sA - sB) * sc);
}

// ---- T1: x[b,t,d] -> Z[b,g,t] (packed pairs, fp16 half2) ----
__global__ __launch_bounds__(256, 8) void k_pack_t(const float2* __restrict__ x2,
                                                   uint32_t* __restrict__ Z) {
  __shared__ float2 tile[64][33];
  const int tid = threadIdx.x;
  const int g0 = blockIdx.x * 32;
  const int t0 = blockIdx.y * 64;
  const int b = blockIdx.z;
#pragma unroll
  for (int it = 0; it < 8; ++it) {
    const int l = tid + 256 * it;
    const int r = l >> 5, c = l & 31;
    tile[r][c] = x2[((size_t)b * T_ + t0 + r) * D2_ + g0 + c];
  }
  __syncthreads();
#pragma unroll
  for (int it = 0; it < 8; ++it) {
    const int l = tid + 256 * it;
    const int gg = l >> 6, tt = l & 63;
    const float2 t = tile[tt][gg];
    Z[((size_t)b * D2_ + g0 + gg) * T_ + t0 + tt] = pk(t.x, t.y);
  }
}

// ---- F: full FFT/filter/iFFT per (g,b), in-place on fp16 Z row ----
__global__ __launch_bounds__(256, 4) void k_fft_fused(uint32_t* __restrict__ Z,
                                                      const float2* __restrict__ HT) {
  __shared__ float2 S[4096];  // 32 KB fp32 (r12-proven)
  const int tid = threadIdx.x;
  const int g = blockIdx.x;
  const int b = blockIdx.y;
  uint32_t* __restrict__ Zrow = Z + ((size_t)b * D2_ + g) * T_;
  const float2* __restrict__ HTg = HT + (size_t)g * NBINS;
  constexpr float C1f = -6.28318530717958647692f / 4096.0f;
  constexpr float C2f = -6.28318530717958647692f / 256.0f;
  constexpr float C1i = 6.28318530717958647692f / 4096.0f;
  constexpr float C2i = 6.28318530717958647692f / 256.0f;

  float vr[16], vi[16];
  // fwd stage 1: thread j: u[a]=z[j+256a]; DFT16 a->r; *W4096^{-rj}; S[256r+j]
  {
    const int j = tid;
#pragma unroll
    for (int a = 0; a < 16; ++a) {
      const float2 t = upk(Zrow[j + 256 * a]);
      vr[a] = t.x; vi[a] = t.y;
    }
    dft16<-1>(vr, vi);
#pragma unroll
    for (int r = 1; r < 16; ++r) twiddle(vr[r], vi[r], C1f * (float)(r * j));
#pragma unroll
    for (int r = 0; r < 16; ++r) S[256 * r + j] = make_float2(vr[r], vi[r]);
  }
  __syncthreads();
  const int rr = tid >> 4, ii = tid & 15;
  // fwd stage 2
  {
#pragma unroll
    for (int a = 0; a < 16; ++a) {
      const float2 t = S[256 * rr + ii + 16 * a];
      vr[a] = t.x; vi[a] = t.y;
    }
    __syncthreads();  // WAR
    dft16<-1>(vr, vi);
#pragma unroll
    for (int r2 = 1; r2 < 16; ++r2) twiddle(vr[r2], vi[r2], C2f * (float)(r2 * ii));
#pragma unroll
    for (int r2 = 0; r2 < 16; ++r2)
      S[256 * ii + 16 * rr + (r2 ^ ii)] = make_float2(vr[r2], vi[r2]);
  }
  __syncthreads();
  // fwd stage 3: vr[s2] = X[k], k = rr + 16*ii + 256*s2
  {
#pragma unroll
    for (int i2 = 0; i2 < 16; ++i2) {
      const float2 t = S[256 * i2 + 16 * rr + (ii ^ i2)];
      vr[i2] = t.x; vi[i2] = t.y;
    }
    __syncthreads();  // WAR
    dft16<-1>(vr, vi);
  }
  // filter: X swizzle-stored Q(k)=256*d2+16*d1+(d0^d1); partner conj from LDS
  float2 hv[16];
  {
#pragma unroll
    for (int s2 = 0; s2 < 16; ++s2) {
      const int k = rr + 16 * ii + 256 * s2;
      const int km = (k <= 2048) ? k : 4096 - k;
      hv[s2] = HTg[km];
    }
#pragma unroll
    for (int s2 = 0; s2 < 16; ++s2)
      S[256 * s2 + 16 * ii + (rr ^ ii)] = make_float2(vr[s2], vi[s2]);
    __syncthreads();
#pragma unroll
    for (int s2 = 0; s2 < 16; ++s2) {
      const int k = rr + 16 * ii + 256 * s2;
      const int kp = (4096 - k) & 4095;
      const int d0 = kp & 15, d1 = (kp >> 4) & 15, d2 = kp >> 8;
      const float2 xp = S[256 * d2 + 16 * d1 + (d0 ^ d1)];
      const float yr = hv[s2].x * vr[s2] + hv[s2].y * xp.x;
      const float yi = hv[s2].x * vi[s2] - hv[s2].y * xp.y;
      vr[s2] = yr; vi[s2] = yi;
    }
  }
  __syncthreads();  // WAR before inv writes
  // inv stage A
  {
    dft16<1>(vr, vi);
#pragma unroll
    for (int j0 = 1; j0 < 16; ++j0) twiddle(vr[j0], vi[j0], C2i * (float)(ii * j0));
#pragma unroll
    for (int j0 = 0; j0 < 16; ++j0)
      S[256 * j0 + 16 * rr + (ii ^ j0)] = make_float2(vr[j0], vi[j0]);
  }
  __syncthreads();
  // inv stage B
  {
#pragma unroll
    for (int r2 = 0; r2 < 16; ++r2) {
      const float2 t = S[256 * ii + 16 * rr + (r2 ^ ii)];
      vr[r2] = t.x; vi[r2] = t.y;
    }
    __syncthreads();  // WAR
    dft16<1>(vr, vi);
#pragma unroll
    for (int j1 = 0; j1 < 16; ++j1)
      twiddle(vr[j1], vi[j1], C1i * (float)(rr * (ii + 16 * j1)));
#pragma unroll
    for (int j1 = 0; j1 < 16; ++j1)
      S[256 * rr + ii + 16 * j1] = make_float2(vr[j1], vi[j1]);
  }
  __syncthreads();
  // inv stage C: thread j: u[r]=S[256r+j]; DFT16; z[j+256a] (1/N already in HT)
  {
    const int j = tid;
#pragma unroll
    for (int r = 0; r < 16; ++r) {
      const float2 t = S[256 * r + j];
      vr[r] = t.x; vi[r] = t.y;
    }
    dft16<1>(vr, vi);
#pragma unroll
    for (int a = 0; a < 16; ++a)
      Zrow[j + 256 * a] = pk(vr[a], vi[a]);
  }
}

// ---- T2: Z[b,g,t] (fp16) -> y[b,t,d], * amp ----
__global__ __launch_bounds__(256, 8) void k_unpack_t(const uint32_t* __restrict__ Z,
                                                     const float2* __restrict__ amp2,
                                                     float2* __restrict__ y2) {
  __shared__ float2 tile[64][33];
  const int tid = threadIdx.x;
  const int g0 = blockIdx.x * 32;
  const int t0 = blockIdx.y * 64;
  const int b = blockIdx.z;
#pragma unroll
  for (int it = 0; it < 8; ++it) {
    const int l = tid + 256 * it;
    const int gg = l >> 6, tt = l & 63;
    tile[tt][gg] = upk(Z[((size_t)b * D2_ + g0 + gg) * T_ + t0 + tt]);
  }
  __syncthreads();
#pragma unroll
  for (int it = 0; it < 8; ++it) {
    const int l = tid + 256 * it;
    const int r = l >> 5, c = l & 31;
    const float2 t = tile[r][c];
    const float2 av = amp2[g0 + c];
    y2[((size_t)b * T_ + t0 + r) * D2_ + g0 + c] = make_float2(t.x * av.x, t.y * av.y);
  }
}

extern "C" void kernel_launch(void* const* d_in, const int* in_sizes, int n_in,
                              void* d_out, int out_size, void* d_ws, size_t ws_size,
                              hipStream_t stream) {
  const float* x = (const float*)d_in[0];
  const float* W1 = (const float*)d_in[1];
  const float* b1 = (const float*)d_in[2];
  const float* W2 = (const float*)d_in[3];
  const float* b2 = (const float*)d_in[4];
  const float* amp = (const float*)d_in[5];
  float* out = (float*)d_out;

  uint32_t* Z = (uint32_t*)d_ws;  // 4*512*4096*4 = 32 MB (fp16 half2)
  float2* HT = (float2*)((char*)d_ws + (size_t)B_ * D2_ * T_ * sizeof(uint32_t));  // 8.4 MB
  float* h = (float*)((char*)HT + (size_t)D2_ * NBINS * sizeof(float2));  // 262 KB

  k_filter_h<<<dim3((NBINS + 255) / 256), 256, 0, stream>>>(W1, b1, h);
  k_filter_HT<<<dim3((NBINS + 255) / 256, D2_), 256, 0, stream>>>(h, W2, b2, HT);
  k_pack_t<<<dim3(D2_ / 32, T_ / 64, B_), 256, 0, stream>>>((const float2*)x, Z);
  k_fft_fused<<<dim3(D2_, B_), 256, 0, stream>>>(Z, HT);
  k_unpack_t<<<dim3(D2_ / 32, T_ / 64, B_), 256, 0, stream>>>(Z, (const float2*)amp,
                                                              (float2*)out);
}